// Round 1
// baseline (2546.746 us; speedup 1.0000x reference)
//
#include <hip/hip_runtime.h>

// GRU: B=256, T=2048, I=2, H=128. One workgroup per batch element,
// 384 threads = 3H gate rows. W_hh row per thread in VGPRs (128 floats),
// h in LDS (broadcast reads), x staged to LDS once.

#define BB 256
#define TT 2048
#define II 2
#define HH 128
#define GG 384   // 3*H

__device__ __forceinline__ float fast_sigmoid(float x) {
    return 1.0f / (1.0f + __expf(-x));
}

__device__ __forceinline__ float fast_tanh(float x) {
    // clamp to avoid inf/inf
    x = fminf(fmaxf(x, -30.0f), 30.0f);
    float e = __expf(2.0f * x);
    return (e - 1.0f) / (e + 1.0f);
}

__global__ __launch_bounds__(GG, 2) void gru_seq_kernel(
    const float* __restrict__ x,        // [B, T, 2]
    const int*   __restrict__ lengths,  // [B]
    const float* __restrict__ W_ih,     // [384, 2]
    const float* __restrict__ W_hh,     // [384, 128]
    const float* __restrict__ b_ih,     // [384]
    const float* __restrict__ b_hh,     // [384]
    const float* __restrict__ head_w,   // [128]
    const float* __restrict__ head_b,   // [1]
    float* __restrict__ out)            // [B]
{
    __shared__ __align__(16) float x_lds[TT * II];  // 16 KB
    __shared__ __align__(16) float h_lds[HH];
    __shared__ float s_lds[GG];

    const int b = blockIdx.x;
    const int g = threadIdx.x;          // 0..383 : gate row
    const int len = lengths[b];

    // --- one-time: W_hh row g into registers (128 VGPRs) ---
    float w[HH];
    const float* wrow = W_hh + g * HH;
    #pragma unroll
    for (int k = 0; k < HH; ++k) w[k] = wrow[k];

    const float bhh = b_hh[g];
    const float wi0 = W_ih[g * II + 0];
    const float wi1 = W_ih[g * II + 1];
    const float bih = b_ih[g];

    // combine-thread (j < 128) params: n-gate input proj + head weight
    float wn0 = 0.f, wn1 = 0.f, bn = 0.f, hw = 0.f;
    if (g < HH) {
        wn0 = W_ih[(2 * HH + g) * II + 0];
        wn1 = W_ih[(2 * HH + g) * II + 1];
        bn  = b_ih[2 * HH + g];
        hw  = head_w[g];
        h_lds[g] = 0.0f;
    }

    // --- stage x[b] into LDS (coalesced) ---
    const float* xb = x + (size_t)b * TT * II;
    for (int i = g; i < TT * II; i += GG) x_lds[i] = xb[i];

    __syncthreads();

    float h_reg = 0.0f;   // h[g] for g < 128

    const float4* h4 = (const float4*)h_lds;

    for (int t = 0; t < len; ++t) {
        const float x0 = x_lds[II * t + 0];
        const float x1 = x_lds[II * t + 1];

        // stage 1: gh[g] = W_hh[g,:] . h + b_hh[g]
        float a0 = bhh, a1 = 0.f, a2 = 0.f, a3 = 0.f;
        #pragma unroll
        for (int k4 = 0; k4 < HH / 4; ++k4) {
            const float4 hv = h4[k4];
            a0 = fmaf(w[4 * k4 + 0], hv.x, a0);
            a1 = fmaf(w[4 * k4 + 1], hv.y, a1);
            a2 = fmaf(w[4 * k4 + 2], hv.z, a2);
            a3 = fmaf(w[4 * k4 + 3], hv.w, a3);
        }
        const float gh = (a0 + a1) + (a2 + a3);

        float val;
        if (g < 2 * HH) {
            // r-rows (0..127) and z-rows (128..255): apply sigmoid(xp + gh)
            const float xp = fmaf(wi0, x0, fmaf(wi1, x1, bih));
            val = fast_sigmoid(xp + gh);
        } else {
            // n-rows: raw hn (includes b_hh); xn added in stage 2
            val = gh;
        }
        s_lds[g] = val;
        __syncthreads();

        // stage 2: threads 0..127 update h
        if (g < HH) {
            const float r  = s_lds[g];
            const float z  = s_lds[HH + g];
            const float hn = s_lds[2 * HH + g];
            const float xn = fmaf(wn0, x0, fmaf(wn1, x1, bn));
            const float n  = fast_tanh(fmaf(r, hn, xn));
            h_reg = n + z * (h_reg - n);   // (1-z)*n + z*h
            h_lds[g] = h_reg;
        }
        __syncthreads();
    }

    // --- head: out[b] = dot(h, head_w) + head_b ---
    float p = (g < HH) ? h_reg * hw : 0.0f;
    s_lds[g] = p;
    __syncthreads();
    if (g < 64) {
        float v = s_lds[g] + s_lds[g + 64] + s_lds[g + 128] +
                  s_lds[g + 192] + s_lds[g + 256] + s_lds[g + 320];
        #pragma unroll
        for (int off = 32; off > 0; off >>= 1)
            v += __shfl_down(v, off, 64);
        if (g == 0) out[b] = v + head_b[0];
    }
}

extern "C" void kernel_launch(void* const* d_in, const int* in_sizes, int n_in,
                              void* d_out, int out_size, void* d_ws, size_t ws_size,
                              hipStream_t stream) {
    const float* x      = (const float*)d_in[0];
    const int*   len    = (const int*)  d_in[1];
    const float* W_ih   = (const float*)d_in[2];
    const float* W_hh   = (const float*)d_in[3];
    const float* b_ih   = (const float*)d_in[4];
    const float* b_hh   = (const float*)d_in[5];
    const float* head_w = (const float*)d_in[6];
    const float* head_b = (const float*)d_in[7];
    float* out = (float*)d_out;

    gru_seq_kernel<<<BB, GG, 0, stream>>>(x, len, W_ih, W_hh, b_ih, b_hh,
                                          head_w, head_b, out);
}

// Round 2
// 1408.598 us; speedup vs baseline: 1.8080x; 1.8080x over previous
//
#include <hip/hip_runtime.h>

// GRU: B=256, T=2048, I=2, H=128. One workgroup (512 thr = 8 waves) per batch.
// Thread (q=tid&3, j=tid>>2) owns 32-col slice q of gate rows {j, 128+j, 256+j}:
// 3x8 float4 weights in VGPRs. h in double-buffered LDS (padded banks),
// read 8x float4/step, reused for all 3 gates. Partial dots combined with
// __shfl_xor(1,2). One __syncthreads per step.

#define BB 256
#define TT 2048
#define HH 128
#define NT 512
// padded h layout: 32-float block q lives at word 40*q (32B pad per block)
#define HWORDS 160

__device__ __forceinline__ float fast_sigmoid(float v) {
    return 1.0f / (1.0f + __expf(-v));
}
__device__ __forceinline__ float fast_tanh(float v) {
    v = fminf(fmaxf(v, -30.0f), 30.0f);
    float e = __expf(2.0f * v);
    return (e - 1.0f) / (e + 1.0f);
}

__global__ __launch_bounds__(NT, 2) void gru_seq_kernel(
    const float* __restrict__ x,        // [B, T, 2]
    const int*   __restrict__ lengths,  // [B]
    const float* __restrict__ W_ih,     // [384, 2]
    const float* __restrict__ W_hh,     // [384, 128]
    const float* __restrict__ b_ih,     // [384]
    const float* __restrict__ b_hh,     // [384]
    const float* __restrict__ head_w,   // [128]
    const float* __restrict__ head_b,   // [1]
    float* __restrict__ out)            // [B]
{
    __shared__ __align__(16) float x_lds[TT * 2];        // 16 KB
    __shared__ __align__(16) float h_lds[2][HWORDS];     // 1.25 KB
    __shared__ float red[8];

    const int tid = threadIdx.x;
    const int q = tid & 3;          // 32-col slice
    const int j = tid >> 2;         // hidden index 0..127
    const int b = blockIdx.x;
    const int len = lengths[b];

    // --- weights for this thread's 3 row-slices (96 VGPRs, small arrays) ---
    float4 wr[8], wz[8], wn[8];
    {
        const float4* Wr = (const float4*)(W_hh + (size_t)j * HH + q * 32);
        const float4* Wz = (const float4*)(W_hh + (size_t)(HH + j) * HH + q * 32);
        const float4* Wn = (const float4*)(W_hh + (size_t)(2 * HH + j) * HH + q * 32);
        #pragma unroll
        for (int i = 0; i < 8; ++i) { wr[i] = Wr[i]; wz[i] = Wz[i]; wn[i] = Wn[i]; }
    }

    // per-j scalar params (only q==0 lane uses them)
    float wir0 = 0.f, wir1 = 0.f, bir = 0.f;
    float wiz0 = 0.f, wiz1 = 0.f, biz = 0.f;
    float win0 = 0.f, win1 = 0.f, bin = 0.f;
    float bhr = 0.f, bhz = 0.f, bhn = 0.f, hw = 0.f;
    if (q == 0) {
        wir0 = W_ih[j * 2];            wir1 = W_ih[j * 2 + 1];            bir = b_ih[j];
        wiz0 = W_ih[(HH + j) * 2];     wiz1 = W_ih[(HH + j) * 2 + 1];     biz = b_ih[HH + j];
        win0 = W_ih[(2 * HH + j) * 2]; win1 = W_ih[(2 * HH + j) * 2 + 1]; bin = b_ih[2 * HH + j];
        bhr = b_hh[j]; bhz = b_hh[HH + j]; bhn = b_hh[2 * HH + j];
        hw = head_w[j];
    }

    // --- stage x[b] into LDS (float4, coalesced) ---
    {
        const float4* xb4 = (const float4*)(x + (size_t)b * TT * 2);
        float4* xl4 = (float4*)x_lds;
        #pragma unroll
        for (int i = tid; i < TT * 2 / 4; i += NT) xl4[i] = xb4[i];
    }
    // zero both h buffers
    for (int i = tid; i < 2 * HWORDS; i += NT) ((float*)h_lds)[i] = 0.f;

    __syncthreads();

    float h_reg = 0.0f;   // h[j] held by q==0 lanes
    int buf = 0;

    for (int t = 0; t < len; ++t) {
        const float x0 = x_lds[2 * t];
        const float x1 = x_lds[2 * t + 1];

        // read this thread's h slice once (banks disjoint across q: word 40*q+4i)
        const float4* hb = (const float4*)&h_lds[buf][40 * q];
        float4 hv[8];
        #pragma unroll
        for (int i = 0; i < 8; ++i) hv[i] = hb[i];

        float ar = 0.f, az = 0.f, an = 0.f;
        #pragma unroll
        for (int i = 0; i < 8; ++i) {
            const float4 h4 = hv[i];
            ar = fmaf(wr[i].x, h4.x, fmaf(wr[i].y, h4.y, fmaf(wr[i].z, h4.z, fmaf(wr[i].w, h4.w, ar))));
            az = fmaf(wz[i].x, h4.x, fmaf(wz[i].y, h4.y, fmaf(wz[i].z, h4.z, fmaf(wz[i].w, h4.w, az))));
            an = fmaf(wn[i].x, h4.x, fmaf(wn[i].y, h4.y, fmaf(wn[i].z, h4.z, fmaf(wn[i].w, h4.w, an))));
        }
        // combine q-slices (adjacent lanes)
        ar += __shfl_xor(ar, 1); ar += __shfl_xor(ar, 2);
        az += __shfl_xor(az, 1); az += __shfl_xor(az, 2);
        an += __shfl_xor(an, 1); an += __shfl_xor(an, 2);

        if (q == 0) {
            const float r  = fast_sigmoid(fmaf(wir0, x0, fmaf(wir1, x1, bir)) + ar + bhr);
            const float z  = fast_sigmoid(fmaf(wiz0, x0, fmaf(wiz1, x1, biz)) + az + bhz);
            const float hn = an + bhn;
            const float xn = fmaf(win0, x0, fmaf(win1, x1, bin));
            const float n  = fast_tanh(fmaf(r, hn, xn));
            h_reg = n + z * (h_reg - n);
            h_lds[buf ^ 1][40 * (j >> 5) + (j & 31)] = h_reg;
        }
        __syncthreads();
        buf ^= 1;
    }

    // --- head: out[b] = dot(h, head_w) + head_b ---
    float p = (q == 0) ? h_reg * hw : 0.0f;
    #pragma unroll
    for (int off = 32; off > 0; off >>= 1) p += __shfl_xor(p, off);
    const int wid = tid >> 6;
    if ((tid & 63) == 0) red[wid] = p;
    __syncthreads();
    if (tid == 0) {
        float s = red[0];
        #pragma unroll
        for (int i = 1; i < 8; ++i) s += red[i];
        out[b] = s + head_b[0];
    }
}

extern "C" void kernel_launch(void* const* d_in, const int* in_sizes, int n_in,
                              void* d_out, int out_size, void* d_ws, size_t ws_size,
                              hipStream_t stream) {
    const float* x      = (const float*)d_in[0];
    const int*   len    = (const int*)  d_in[1];
    const float* W_ih   = (const float*)d_in[2];
    const float* W_hh   = (const float*)d_in[3];
    const float* b_ih   = (const float*)d_in[4];
    const float* b_hh   = (const float*)d_in[5];
    const float* head_w = (const float*)d_in[6];
    const float* head_b = (const float*)d_in[7];
    float* out = (float*)d_out;

    gru_seq_kernel<<<BB, NT, 0, stream>>>(x, len, W_ih, W_hh, b_ih, b_hh,
                                          head_w, head_b, out);
}